// Round 1
// baseline (476.152 us; speedup 1.0000x reference)
//
#include <hip/hip_runtime.h>

// EnsembleLayer: y[b, n*32+c] = sum_c' M[n][c][c'] * x[b, clusters[n][c']] + bias[n][c]
// where M[n] = dec_w[n] @ enc_w[n]  (fused encoder+decoder, same FLOPs, one pass)
//
// B=131072, F=512, NC=16, CS=32, NH=16. Memory-bound: 537 MB traffic -> ~90us floor.

#define B_ROWS   131072
#define F        512
#define NC       16
#define CS       32
#define NH       16
#define NBLOCKS  1024
#define RPB      128   // rows per block (B_ROWS / NBLOCKS)
#define RPI      8     // rows per iteration
#define NITER    (RPB / RPI)

__global__ __launch_bounds__(256, 4)
void ensemble_kernel(const float* __restrict__ x,
                     const int*   __restrict__ clusters,
                     const float* __restrict__ enc_w,
                     const float* __restrict__ enc_b,
                     const float* __restrict__ dec_w,
                     const float* __restrict__ dec_b,
                     float*       __restrict__ out) {
    // xi tile, swizzled within each cluster row: value xi[n*32+c] stored at
    // slot n*32 + ((c + 4n) & 31)  -> per-k b128 reads across lanes hit 16
    // distinct banks (conflict-free broadcast).
    __shared__ float s_xi[RPI][F];
    __shared__ int   s_tgt[F];   // s_tgt[src_col] = swizzled LDS slot

    const int t = threadIdx.x;

    // ---- build inverse-permutation target table (once per block) ----
    for (int j = t; j < F; j += 256) {
        int col = clusters[j];                 // xi position j sources x column col
        int nn = j >> 5, cc = j & 31;
        s_tgt[col] = (nn << 5) | ((cc + (nn << 2)) & 31);
    }
    __syncthreads();

    // cache my 4 scatter targets (I always load the same 4 source columns)
    const int cbase = (t & 127) << 2;
    const int tgt0 = s_tgt[cbase + 0];
    const int tgt1 = s_tgt[cbase + 1];
    const int tgt2 = s_tgt[cbase + 2];
    const int tgt3 = s_tgt[cbase + 3];

    // ---- compute my fused M rows + biases (registers) ----
    // thread owns cluster n, output columns c0 and c0+1
    const int n  = t >> 4;
    const int c0 = (t & 15) << 1;

    float m0[32], m1[32];
    #pragma unroll
    for (int i = 0; i < 32; ++i) { m0[i] = 0.f; m1[i] = 0.f; }
    float b0 = dec_b[n * CS + c0];
    float b1 = dec_b[n * CS + c0 + 1];

    for (int h = 0; h < NH; ++h) {
        const float d0 = dec_w[(n * CS + c0)     * NH + h];
        const float d1 = dec_w[(n * CS + c0 + 1) * NH + h];
        const float eb = enc_b[n * NH + h];
        b0 += d0 * eb;
        b1 += d1 * eb;
        const float4* ew = (const float4*)(enc_w + (n * NH + h) * CS);
        #pragma unroll
        for (int k = 0; k < 8; ++k) {
            float4 e = ew[k];
            m0[4*k+0] += d0 * e.x;  m1[4*k+0] += d1 * e.x;
            m0[4*k+1] += d0 * e.y;  m1[4*k+1] += d1 * e.y;
            m0[4*k+2] += d0 * e.z;  m1[4*k+2] += d1 * e.z;
            m0[4*k+3] += d0 * e.w;  m1[4*k+3] += d1 * e.w;
        }
    }

    // ---- main loop: 8 rows per iteration ----
    const int rhalf = t >> 7;                  // which of 2 rows this thread loads per pass
    const int row_block = blockIdx.x * RPB;
    const int xioff = n << 5;                  // my cluster's base slot in a xi row

    for (int it = 0; it < NITER; ++it) {
        const int r0 = row_block + it * RPI;

        // coalesced float4 loads of 8 rows (independent of LDS -> scheduled early)
        float4 v[4];
        #pragma unroll
        for (int p = 0; p < 4; ++p) {
            const float* src = x + (size_t)(r0 + p * 2 + rhalf) * F + cbase;
            v[p] = *(const float4*)src;
        }

        __syncthreads();   // previous iteration's xi reads complete

        // scatter into permuted+swizzled LDS slots
        #pragma unroll
        for (int p = 0; p < 4; ++p) {
            float* dst = s_xi[p * 2 + rhalf];
            dst[tgt0] = v[p].x;
            dst[tgt1] = v[p].y;
            dst[tgt2] = v[p].z;
            dst[tgt3] = v[p].w;
        }

        __syncthreads();

        // compute 8 rows: each thread 2 outputs, 64 FMAs/row
        #pragma unroll
        for (int r = 0; r < RPI; ++r) {
            float a0 = b0, a1 = b1;
            const float* xr = &s_xi[r][xioff];
            #pragma unroll
            for (int k = 0; k < 8; ++k) {
                const int kk = (k + n) & 7;            // swizzled slot holding c=4k..4k+3
                float4 xv = *(const float4*)(xr + (kk << 2));
                a0 += m0[4*k+0] * xv.x;  a1 += m1[4*k+0] * xv.x;
                a0 += m0[4*k+1] * xv.y;  a1 += m1[4*k+1] * xv.y;
                a0 += m0[4*k+2] * xv.z;  a1 += m1[4*k+2] * xv.z;
                a0 += m0[4*k+3] * xv.w;  a1 += m1[4*k+3] * xv.w;
            }
            float2 o = make_float2(a0, a1);
            *(float2*)(out + (size_t)(r0 + r) * F + xioff + c0) = o;
        }
    }
}

extern "C" void kernel_launch(void* const* d_in, const int* in_sizes, int n_in,
                              void* d_out, int out_size, void* d_ws, size_t ws_size,
                              hipStream_t stream) {
    const float* x      = (const float*)d_in[0];
    const int*   clus   = (const int*)  d_in[1];
    const float* enc_w  = (const float*)d_in[2];
    const float* enc_b  = (const float*)d_in[3];
    const float* dec_w  = (const float*)d_in[4];
    const float* dec_b  = (const float*)d_in[5];
    float*       out    = (float*)d_out;

    ensemble_kernel<<<NBLOCKS, 256, 0, stream>>>(x, clus, enc_w, enc_b, dec_w, dec_b, out);
}